// Round 1
// 270.709 us; speedup vs baseline: 1.0278x; 1.0278x over previous
//
#include <hip/hip_runtime.h>

// out = softmax(out_state @ W @ history^T, axis=-1); bias drops out of softmax.
// STATE_LEN=2048, SEQ_LEN=4096, HIDDEN=2048, fp32 in/out.
// Precision: split-bf16 (hi+lo), 3-term MFMA (hh+hl+lh) -> ~4e-3 absmax.
//
// R11: fatten wave tile 64x64 -> 64x128. 256x256 block, 8 waves (4x2), BK=32,
// 128 KiB LDS double-buffer, same proven raw-barrier + counted-vmcnt(8)
// discipline as R10. Per-CU per K-step: ds_read 8wx24=192 b128 (~2304cy) vs
// MFMA 8wx96=768... (3725cy) -> serialized ceiling 62% (was 48%).
// Both GEMMs unified on this kernel; d_out doubles as partial scratch so the
// workspace footprint stays 96 MB; softmax fuses the KSPLIT=2 partial add.

#define STATE_LEN 2048
#define SEQ_LEN   4096
#define HIDDEN    2048

#define BK 32

// gfx9 s_waitcnt imm: vmcnt[3:0]=b3:0,[5:4]=b15:14; exp=b6:4; lgkm=b11:8
#define WAIT_VM8   0x0F78  // vmcnt(8),  lgkm=15, exp=7
#define WAIT_VM0   0x0F70  // vmcnt(0),  lgkm=15, exp=7
#define WAIT_LGKM0 0xC07F  // lgkmcnt(0), vmcnt=63, exp=7

typedef __bf16 bf16x8 __attribute__((ext_vector_type(8)));
typedef float f32x4 __attribute__((ext_vector_type(4)));

__device__ __forceinline__ unsigned short f32_to_bf16(float f) {
  unsigned u = __float_as_uint(f);
  u += 0x7FFFu + ((u >> 16) & 1u);   // round-to-nearest-even
  return (unsigned short)(u >> 16);
}
__device__ __forceinline__ float bf16_to_f32(unsigned short h) {
  return __uint_as_float(((unsigned)h) << 16);
}

__device__ __forceinline__ void gld16(const void* g, void* l) {
  __builtin_amdgcn_global_load_lds(
      (const __attribute__((address_space(1))) unsigned int*)g,
      (__attribute__((address_space(3))) unsigned int*)l,
      16, 0, 0);
}

// ---------------- fused pack: W-transpose FIRST, then splits ----------------
// jobs by flat blockIdx.x:
//   [0,1024)      : transpose+split W, 64x64 tile per block (longest -> first)
//   [1024,5120)   : split out_state (4M elems, 1024 elems/block)
//   [5120,13312)  : split history   (8M elems)
__global__ __launch_bounds__(256) void pack_all(
    const float* __restrict__ os, const float* __restrict__ hist,
    const float* __restrict__ W,
    unsigned short* __restrict__ ohi, unsigned short* __restrict__ olo,
    unsigned short* __restrict__ hhi, unsigned short* __restrict__ hlo,
    unsigned short* __restrict__ wthi, unsigned short* __restrict__ wtlo) {
  const int bx = blockIdx.x;
  const int t = threadIdx.x;
  if (bx >= 1024) {
    const int b2 = bx - 1024;
    const float* in;
    unsigned short *hi, *lo;
    int i;
    if (b2 < 4096) {
      in = os; hi = ohi; lo = olo; i = (b2 * 256 + t) * 4;
    } else {
      in = hist; hi = hhi; lo = hlo; i = ((b2 - 4096) * 256 + t) * 4;
    }
    float4 v = *(const float4*)&in[i];
    ushort4 h, l;
    h.x = f32_to_bf16(v.x); l.x = f32_to_bf16(v.x - bf16_to_f32(h.x));
    h.y = f32_to_bf16(v.y); l.y = f32_to_bf16(v.y - bf16_to_f32(h.y));
    h.z = f32_to_bf16(v.z); l.z = f32_to_bf16(v.z - bf16_to_f32(h.z));
    h.w = f32_to_bf16(v.w); l.w = f32_to_bf16(v.w - bf16_to_f32(h.w));
    *(ushort4*)&hi[i] = h;
    *(ushort4*)&lo[i] = l;
  } else {
    // transpose 64x64 tile: Wt[k][h] = W[h][k]
    __shared__ float tile[64][65];
    const int bt = bx;                  // 32x32 tiles
    const int h0 = (bt & 31) * 64;      // W row base
    const int k0 = (bt >> 5) * 64;      // W col base
    const int lr = t >> 4;
    const int c4 = (t & 15) * 4;
#pragma unroll
    for (int pass = 0; pass < 4; ++pass) {
      const int row = pass * 16 + lr;
      float4 v = *(const float4*)&W[(size_t)(h0 + row) * HIDDEN + k0 + c4];
      tile[row][c4] = v.x; tile[row][c4 + 1] = v.y;
      tile[row][c4 + 2] = v.z; tile[row][c4 + 3] = v.w;
    }
    __syncthreads();
#pragma unroll
    for (int pass = 0; pass < 4; ++pass) {
      const int kl = pass * 16 + (t >> 4);
      const int hl = (t & 15) * 4;
      ushort4 h4, l4;
#pragma unroll
      for (int j = 0; j < 4; ++j) {
        const float x = tile[hl + j][kl];
        const unsigned short h = f32_to_bf16(x);
        ((unsigned short*)&h4)[j] = h;
        ((unsigned short*)&l4)[j] = f32_to_bf16(x - bf16_to_f32(h));
      }
      const size_t o = (size_t)(k0 + kl) * HIDDEN + h0 + hl;
      *(ushort4*)&wthi[o] = h4;
      *(ushort4*)&wtlo[o] = l4;
    }
  }
}

// ---- p0+p1+p2+p3 -> split bf16 (hi/lo) ----
__global__ __launch_bounds__(256) void reduce_split4(
    const float* __restrict__ p0, const float* __restrict__ p1,
    const float* __restrict__ p2, const float* __restrict__ p3,
    unsigned short* __restrict__ hi, unsigned short* __restrict__ lo, int n) {
  int i = (blockIdx.x * 256 + threadIdx.x) * 4;
  if (i >= n) return;
  float4 a = *(const float4*)&p0[i];
  float4 b = *(const float4*)&p1[i];
  float4 c = *(const float4*)&p2[i];
  float4 d = *(const float4*)&p3[i];
  a.x = (a.x + b.x) + (c.x + d.x);
  a.y = (a.y + b.y) + (c.y + d.y);
  a.z = (a.z + b.z) + (c.z + d.z);
  a.w = (a.w + b.w) + (c.w + d.w);
  ushort4 h, l;
  h.x = f32_to_bf16(a.x); l.x = f32_to_bf16(a.x - bf16_to_f32(h.x));
  h.y = f32_to_bf16(a.y); l.y = f32_to_bf16(a.y - bf16_to_f32(h.y));
  h.z = f32_to_bf16(a.z); l.z = f32_to_bf16(a.z - bf16_to_f32(h.z));
  h.w = f32_to_bf16(a.w); l.w = f32_to_bf16(a.w - bf16_to_f32(h.w));
  *(ushort4*)&hi[i] = h;
  *(ushort4*)&lo[i] = l;
}

// -------- 256x256 split-bf16 GEMM, C[m][n] = sum_k A[m][k]*B[n][k] --------
// 8 waves (4Mx2N), wave tile 64x128 (4x8 frags of 16x16x32), BK=32, dbuf LDS
// 128 KiB, 1 block/CU. LDS swizzle: slot (row,c) holds chunk c^((r>>1)&3)
// via pre-swizzled global source (gld16 dest must be linear: base+lane*16).
// Raw s_barrier + manual vmcnt(8): next tile's 8 DMAs/thread stay in flight
// across the MFMA block (same proven pattern as R10).
// KSPLIT>1: blockIdx.z selects fp32 partial buffer P0..P3.
template <int KSPLIT>
__global__ __launch_bounds__(512, 2) void gemm_big(
    const unsigned short* __restrict__ Ahi, const unsigned short* __restrict__ Alo,
    const unsigned short* __restrict__ Bhi, const unsigned short* __restrict__ Blo,
    float* __restrict__ P0, float* __restrict__ P1,
    float* __restrict__ P2, float* __restrict__ P3,
    int M, int N, int K) {
  __shared__ __align__(16) unsigned short sA[2][2][256 * BK];  // [buf][hi/lo] 64KB
  __shared__ __align__(16) unsigned short sB[2][2][256 * BK];  // 64KB

  const int t = threadIdx.x;           // 0..511 (8 waves)
  const int tileM = blockIdx.y * 256;
  const int tileN = blockIdx.x * 256;
  const int z = (KSPLIT > 1) ? blockIdx.z : 0;
  const int kBase = z * (K / KSPLIT);
  const int iters = (K / KSPLIT) / BK;
  float* Cf = (z == 0) ? P0 : (z == 1) ? P1 : (z == 2) ? P2 : P3;

  const int rr = t >> 2;               // staging row within a 128-row group
  const int cc = t & 3;                // fixed LDS 16B-slot index

  const int lane = t & 63;
  const int wave = t >> 6;
  const int wm = wave >> 1;            // 4x2 wave grid, wave tile 64x128
  const int wn = wave & 1;
  const int lr = lane & 15;
  const int kqc = lane >> 4;           // fragment k-chunk (16B units)

  f32x4 acc[4][8] = {};

  // stage tile into buffer (8 gld16 per thread, wave-uniform linear dest)
  auto stage = [&](int buf, int k0) {
#pragma unroll
    for (int p = 0; p < 2; ++p) {
      const int r = p * 128 + rr;
      const int q = cc ^ ((r >> 1) & 3);  // swizzle via global addr
      const size_t ga = (size_t)(tileM + r) * K + k0 + q * 8;
      const size_t gb = (size_t)(tileN + r) * K + k0 + q * 8;
      const int ls = r * BK + cc * 8;     // == wave_base + lane*16 bytes
      gld16(Ahi + ga, &sA[buf][0][ls]);
      gld16(Alo + ga, &sA[buf][1][ls]);
      gld16(Bhi + gb, &sB[buf][0][ls]);
      gld16(Blo + gb, &sB[buf][1][ls]);
    }
  };

  stage(0, kBase);

  for (int it = 0; it < iters; ++it) {
    const int buf = it & 1;
    if (it + 1 < iters) {
      stage(buf ^ 1, kBase + (it + 1) * BK);
      __builtin_amdgcn_s_waitcnt(WAIT_VM8);  // oldest 8 (= this tile) done
    } else {
      __builtin_amdgcn_s_waitcnt(WAIT_VM0);
    }
    __builtin_amdgcn_s_barrier();            // all waves staged buf

    bf16x8 ah[4], al[4];
#pragma unroll
    for (int mi = 0; mi < 4; ++mi) {
      const int R = wm * 64 + mi * 16 + lr;
      const int off = R * BK + (kqc ^ ((R >> 1) & 3)) * 8;
      ah[mi] = *(const bf16x8*)&sA[buf][0][off];
      al[mi] = *(const bf16x8*)&sA[buf][1][off];
    }
    // two ni-halves: bounds B-frag register pressure (acc128 + A32 + B32)
#pragma unroll
    for (int nh = 0; nh < 2; ++nh) {
      bf16x8 bh[4], bl[4];
#pragma unroll
      for (int nj = 0; nj < 4; ++nj) {
        const int R = wn * 128 + (nh * 4 + nj) * 16 + lr;
        const int off = R * BK + (kqc ^ ((R >> 1) & 3)) * 8;
        bh[nj] = *(const bf16x8*)&sB[buf][0][off];
        bl[nj] = *(const bf16x8*)&sB[buf][1][off];
      }
#pragma unroll
      for (int mi = 0; mi < 4; ++mi)
#pragma unroll
        for (int nj = 0; nj < 4; ++nj) {
          f32x4 a = acc[mi][nh * 4 + nj];
          a = __builtin_amdgcn_mfma_f32_16x16x32_bf16(ah[mi], bh[nj], a, 0, 0, 0);
          a = __builtin_amdgcn_mfma_f32_16x16x32_bf16(ah[mi], bl[nj], a, 0, 0, 0);
          a = __builtin_amdgcn_mfma_f32_16x16x32_bf16(al[mi], bh[nj], a, 0, 0, 0);
          acc[mi][nh * 4 + nj] = a;
        }
    }

    __builtin_amdgcn_s_waitcnt(WAIT_LGKM0);  // frag reads landed in regs
    __builtin_amdgcn_s_barrier();            // safe to overwrite buf next iter
  }

  // epilogue: C/D layout col=lane&15, row=(lane>>4)*4+reg
#pragma unroll
  for (int mi = 0; mi < 4; ++mi)
#pragma unroll
    for (int ni = 0; ni < 8; ++ni)
#pragma unroll
      for (int e = 0; e < 4; ++e) {
        const int row = tileM + wm * 64 + mi * 16 + (lane >> 4) * 4 + e;
        const int col = tileN + wn * 128 + ni * 16 + lr;
        Cf[(size_t)row * N + col] = acc[mi][ni][e];
      }
}

// ------- in-place row softmax over 4096 columns, fusing the p0+p1 add -------
__global__ __launch_bounds__(256) void softmax_rows2(
    float* __restrict__ d, const float* __restrict__ p1, int cols) {
  const int row = blockIdx.x;
  float* p = d + (size_t)row * cols;
  const float* q = p1 + (size_t)row * cols;
  const int t = threadIdx.x;
  const int lane = t & 63;
  const int wave = t >> 6;
  __shared__ float sred[4];

  float4 v[4];
  float m = -3.0e38f;
#pragma unroll
  for (int k = 0; k < 4; ++k) {
    float4 a = *(const float4*)&p[(t + k * 256) * 4];
    float4 b = *(const float4*)&q[(t + k * 256) * 4];
    a.x += b.x; a.y += b.y; a.z += b.z; a.w += b.w;
    v[k] = a;
    m = fmaxf(m, fmaxf(fmaxf(a.x, a.y), fmaxf(a.z, a.w)));
  }
#pragma unroll
  for (int off = 32; off > 0; off >>= 1) m = fmaxf(m, __shfl_xor(m, off, 64));
  if (lane == 0) sred[wave] = m;
  __syncthreads();
  m = fmaxf(fmaxf(sred[0], sred[1]), fmaxf(sred[2], sred[3]));
  __syncthreads();

  float s = 0.f;
#pragma unroll
  for (int k = 0; k < 4; ++k) {
    v[k].x = __expf(v[k].x - m);
    v[k].y = __expf(v[k].y - m);
    v[k].z = __expf(v[k].z - m);
    v[k].w = __expf(v[k].w - m);
    s += (v[k].x + v[k].y) + (v[k].z + v[k].w);
  }
#pragma unroll
  for (int off = 32; off > 0; off >>= 1) s += __shfl_xor(s, off, 64);
  if (lane == 0) sred[wave] = s;
  __syncthreads();
  s = (sred[0] + sred[1]) + (sred[2] + sred[3]);
  const float inv = 1.0f / s;
#pragma unroll
  for (int k = 0; k < 4; ++k) {
    v[k].x *= inv; v[k].y *= inv; v[k].z *= inv; v[k].w *= inv;
    *(float4*)&p[(t + k * 256) * 4] = v[k];
  }
}

extern "C" void kernel_launch(void* const* d_in, const int* in_sizes, int n_in,
                              void* d_out, int out_size, void* d_ws, size_t ws_size,
                              hipStream_t stream) {
  const float* out_state = (const float*)d_in[0];  // [2048, 2048]
  const float* history   = (const float*)d_in[1];  // [4096, 2048]
  const float* W         = (const float*)d_in[2];  // [2048, 2048]
  // d_in[3] = b : softmax-invariant, unused.
  float* out = (float*)d_out;                      // [2048, 4096] fp32

  char* ws = (char*)d_ws;
  const size_t MB = 1ull << 20;
  unsigned short* ohi  = (unsigned short*)(ws + 0 * MB);   // 8 MB
  unsigned short* olo  = (unsigned short*)(ws + 8 * MB);   // 8 MB
  unsigned short* wthi = (unsigned short*)(ws + 16 * MB);  // 8 MB
  unsigned short* wtlo = (unsigned short*)(ws + 24 * MB);  // 8 MB
  unsigned short* hhi  = (unsigned short*)(ws + 32 * MB);  // 16 MB
  unsigned short* hlo  = (unsigned short*)(ws + 48 * MB);  // 16 MB
  float*          pws  = (float*)(ws + 64 * MB);           // 32 MB fp32 partials

  const size_t QSZ = (size_t)STATE_LEN * HIDDEN;           // 4M elems = 16 MB
  // GEMM1 partials: 2 in ws, 2 in d_out (d_out is dead until GEMM2)
  float* g1p0 = pws;
  float* g1p1 = pws + QSZ;
  float* g1p2 = out;
  float* g1p3 = out + QSZ;
  // T split reuses ws[0:16] (out_state split dead after GEMM1)
  unsigned short* thi = (unsigned short*)(ws + 0 * MB);
  unsigned short* tlo = (unsigned short*)(ws + 8 * MB);

  // 1) all packing in one kernel: transpose W (1024 blocks, longest, FIRST) +
  //    split os (4096) + split hist (8192)
  pack_all<<<13312, 256, 0, stream>>>(out_state, history, W, ohi, olo, hhi, hlo,
                                      wthi, wtlo);
  // 2) T partials: 256x256 tiles, KSPLIT=4 -> 8x8x4 = 256 blocks (1/CU)
  gemm_big<4><<<dim3(HIDDEN / 256, STATE_LEN / 256, 4), 512, 0, stream>>>(
      ohi, olo, wthi, wtlo, g1p0, g1p1, g1p2, g1p3, STATE_LEN, HIDDEN, HIDDEN);
  // 3) T = p0+p1+p2+p3 -> split bf16
  reduce_split4<<<(STATE_LEN * HIDDEN) / 1024, 256, 0, stream>>>(
      g1p0, g1p1, g1p2, g1p3, thi, tlo, STATE_LEN * HIDDEN);
  // 4) scores partials: KSPLIT=2 -> 16x8x2 = 256 blocks; z=0 -> d_out,
  //    z=1 -> pws (GEMM1 ws-partials dead after reduce)
  gemm_big<2><<<dim3(SEQ_LEN / 256, STATE_LEN / 256, 2), 512, 0, stream>>>(
      thi, tlo, hhi, hlo, out, pws, nullptr, nullptr, STATE_LEN, SEQ_LEN, HIDDEN);
  // 5) row softmax in place, fusing the partial add
  softmax_rows2<<<STATE_LEN, 256, 0, stream>>>(out, pws, SEQ_LEN);
}